// Round 7
// baseline (311.541 us; speedup 1.0000x reference)
//
#include <hip/hip_runtime.h>
#include <hip/hip_bf16.h>
#include <stdint.h>

#define T_STEPS 86
#define HDIM    64
#define VOCABSZ 257

typedef __attribute__((ext_vector_type(8))) short short8;
typedef __attribute__((ext_vector_type(4))) float f32x4;

__device__ __forceinline__ ushort f2bf(float x){
    union { float f; uint32_t u; } v; v.f = x;
    uint32_t r = v.u + 0x7fffu + ((v.u >> 16) & 1u);
    return (ushort)(r >> 16);
}
__device__ __forceinline__ float bf2f(ushort h){
    union { uint32_t u; float f; } v; v.u = ((uint32_t)h) << 16;
    return v.f;
}
__device__ __forceinline__ float sig_(float x){
    return __fdividef(1.f, 1.f + __expf(-x));
}
__device__ __forceinline__ float tanh_(float x){
    float e = __expf(2.f * x);
    return 1.f - __fdividef(2.f, e + 1.f);
}

// ===== Prep: pack wte to hi|lo dwords; pack lm_W into MFMA B-frag layout =====
__global__ __launch_bounds__(256) void prep_pack(
    const float* __restrict__ wte,
    const float* __restrict__ lm_W,
    uint32_t*    __restrict__ wte_pack,   // [257*64] dwords
    ushort*      __restrict__ lm_frag)    // [17][2][512] ushorts (frag layout)
{
    const int i = blockIdx.x * 256 + threadIdx.x;
    if (i < VOCABSZ * HDIM) {
        const float f = wte[i];
        const ushort hh = f2bf(f);
        const ushort hl = f2bf(f - bf2f(hh));
        wte_pack[i] = (uint32_t)hh | ((uint32_t)hl << 16);
    }
    if (i < 17 * 2 * 64) {
        const int n = i >> 7, rem = i & 127, kt = rem >> 6, l = rem & 63;
        const int col = n * 16 + (l & 15);
        const int k0  = kt * 32 + (l >> 4) * 8;
        short8 h8;
#pragma unroll
        for (int e = 0; e < 8; ++e)
            h8[e] = (col < VOCABSZ) ? (short)f2bf(lm_W[col * HDIM + k0 + e]) : (short)0;
        *(short8*)(lm_frag + (size_t)i * 8) = h8;
    }
}

// ===== Kernel A: recurrence, gate-paired columns, ONE barrier per step =======
// Wave w owns dims d in [8w, 8w+8). acc0 cols = [i(d) | f(d)], acc1 = [g | o].
// i/f/g/o for (row, d) pair up via a single shfl_xor(8) -> elementwise LSTM is
// entirely in-wave; h goes to double-buffered packed LDS; 1 barrier/step.
__global__ __launch_bounds__(512) void lstm_recur3(
    const int*      __restrict__ idx,
    const uint32_t* __restrict__ wte_pack,
    const float*    __restrict__ W_ih,
    const float*    __restrict__ W_hh,
    const float*    __restrict__ b_ih,
    const float*    __restrict__ b_hh,
    uint32_t*       __restrict__ h_pack)  // [B][T][64] dwords hi|lo
{
    __shared__ __align__(16) uint32_t hd[2][16 * 68];   // stride 68 -> bank spread
    __shared__ int idx_lds[16][T_STEPS];

    const int tid  = threadIdx.x;
    const int wave = tid >> 6;
    const int lane = tid & 63;
    const int lmod = lane & 15;
    const int lhi  = lane >> 4;
    const int rbase = blockIdx.x * 16;

    const int d    = wave * 8 + (lmod & 7);
    const int col0 = (lmod < 8) ? d        : 64 + d;    // i | f
    const int col1 = (lmod < 8) ? 128 + d  : 192 + d;   // g | o

    // pack gate-weight B-frags hi+lo for col0/col1
    short8 wbh[2][4], wbl[2][4];
    const float gb0 = b_ih[col0] + b_hh[col0];
    const float gb1 = b_ih[col1] + b_hh[col1];
#pragma unroll
    for (int kt = 0; kt < 4; ++kt) {
        const int k0 = (kt & 1) * 32 + lhi * 8;
        const float* s0 = (kt < 2 ? W_ih : W_hh) + col0 * HDIM + k0;
        const float* s1 = (kt < 2 ? W_ih : W_hh) + col1 * HDIM + k0;
        short8 h0, l0, h1, l1;
#pragma unroll
        for (int e = 0; e < 8; ++e) {
            float f0 = s0[e], f1 = s1[e];
            ushort a = f2bf(f0); h0[e] = (short)a; l0[e] = (short)f2bf(f0 - bf2f(a));
            ushort b = f2bf(f1); h1[e] = (short)b; l1[e] = (short)f2bf(f1 - bf2f(b));
        }
        wbh[0][kt] = h0; wbl[0][kt] = l0;
        wbh[1][kt] = h1; wbl[1][kt] = l1;
    }

    // stage idx; zero h double-buffer
    for (int i = tid; i < 16 * T_STEPS; i += 512) {
        const int r = i / T_STEPS, tt = i % T_STEPS;
        idx_lds[r][tt] = idx[(rbase + r) * T_STEPS + tt];
    }
    for (int i = tid; i < 2 * 16 * 68; i += 512) hd[0][i] = 0;   // flat across both bufs
    __syncthreads();

    // preload emb(0) into register frags
    short8 aeh[2], ael[2];
    {
        const int tok = idx_lds[lmod][0];
        const uint32_t* sp = wte_pack + tok * HDIM + lhi * 8;
#pragma unroll
        for (int kt = 0; kt < 2; ++kt) {
            const uint4 q0 = *(const uint4*)(sp + kt * 32);
            const uint4 q1 = *(const uint4*)(sp + kt * 32 + 4);
            const uint32_t q[8] = {q0.x, q0.y, q0.z, q0.w, q1.x, q1.y, q1.z, q1.w};
            short8 a_, b_;
#pragma unroll
            for (int e = 0; e < 8; ++e) { a_[e] = (short)(q[e] & 0xffffu); b_[e] = (short)(q[e] >> 16); }
            aeh[kt] = a_; ael[kt] = b_;
        }
    }

    float cst[4] = {0.f, 0.f, 0.f, 0.f};

    for (int t = 0; t < T_STEPS; ++t) {
        const int rb = (t & 1) ^ 1, wb = t & 1;

        // h(t-1) frags from LDS (kt 2,3)
        short8 hfh[2], hfl[2];
#pragma unroll
        for (int ktl = 0; ktl < 2; ++ktl) {
            const uint32_t* bp = &hd[rb][lmod * 68 + ktl * 32 + lhi * 8];
            const uint4 q0 = *(const uint4*)(bp);
            const uint4 q1 = *(const uint4*)(bp + 4);
            const uint32_t q[8] = {q0.x, q0.y, q0.z, q0.w, q1.x, q1.y, q1.z, q1.w};
            short8 a_, b_;
#pragma unroll
            for (int e = 0; e < 8; ++e) { a_[e] = (short)(q[e] & 0xffffu); b_[e] = (short)(q[e] >> 16); }
            hfh[ktl] = a_; hfl[ktl] = b_;
        }

        // issue emb(t+1) prefetch early (consumed after EW)
        const int tnext = (t + 1 < T_STEPS) ? (t + 1) : (T_STEPS - 1);
        const int tok2 = idx_lds[lmod][tnext];
        const uint32_t* pp = wte_pack + tok2 * HDIM + lhi * 8;
        const uint4 p0 = *(const uint4*)(pp);
        const uint4 p1 = *(const uint4*)(pp + 4);
        const uint4 p2 = *(const uint4*)(pp + 32);
        const uint4 p3 = *(const uint4*)(pp + 36);

        // gates MFMA: 4 kt x 3 terms x 2 accs
        f32x4 acc0 = {gb0, gb0, gb0, gb0};
        f32x4 acc1 = {gb1, gb1, gb1, gb1};
#pragma unroll
        for (int kt = 0; kt < 2; ++kt) {
            acc0 = __builtin_amdgcn_mfma_f32_16x16x32_bf16(aeh[kt], wbh[0][kt], acc0, 0, 0, 0);
            acc0 = __builtin_amdgcn_mfma_f32_16x16x32_bf16(aeh[kt], wbl[0][kt], acc0, 0, 0, 0);
            acc0 = __builtin_amdgcn_mfma_f32_16x16x32_bf16(ael[kt], wbh[0][kt], acc0, 0, 0, 0);
            acc1 = __builtin_amdgcn_mfma_f32_16x16x32_bf16(aeh[kt], wbh[1][kt], acc1, 0, 0, 0);
            acc1 = __builtin_amdgcn_mfma_f32_16x16x32_bf16(aeh[kt], wbl[1][kt], acc1, 0, 0, 0);
            acc1 = __builtin_amdgcn_mfma_f32_16x16x32_bf16(ael[kt], wbh[1][kt], acc1, 0, 0, 0);
        }
#pragma unroll
        for (int ktl = 0; ktl < 2; ++ktl) {
            acc0 = __builtin_amdgcn_mfma_f32_16x16x32_bf16(hfh[ktl], wbh[0][2 + ktl], acc0, 0, 0, 0);
            acc0 = __builtin_amdgcn_mfma_f32_16x16x32_bf16(hfh[ktl], wbl[0][2 + ktl], acc0, 0, 0, 0);
            acc0 = __builtin_amdgcn_mfma_f32_16x16x32_bf16(hfl[ktl], wbh[0][2 + ktl], acc0, 0, 0, 0);
            acc1 = __builtin_amdgcn_mfma_f32_16x16x32_bf16(hfh[ktl], wbh[1][2 + ktl], acc1, 0, 0, 0);
            acc1 = __builtin_amdgcn_mfma_f32_16x16x32_bf16(hfh[ktl], wbl[1][2 + ktl], acc1, 0, 0, 0);
            acc1 = __builtin_amdgcn_mfma_f32_16x16x32_bf16(hfl[ktl], wbh[1][2 + ktl], acc1, 0, 0, 0);
        }

        // pair gates in-wave + elementwise LSTM (rows lhi*4+e, dim d)
#pragma unroll
        for (int e = 0; e < 4; ++e) {
            const float a0 = acc0[e], a1 = acc1[e];
            const float q0 = __shfl_xor(a0, 8);
            const float q1 = __shfl_xor(a1, 8);
            const float iv = (lmod < 8) ? a0 : q0;
            const float fv = (lmod < 8) ? q0 : a0;
            const float gv = (lmod < 8) ? a1 : q1;
            const float ov = (lmod < 8) ? q1 : a1;
            const float cn = sig_(fv) * cst[e] + sig_(iv) * tanh_(gv);
            cst[e] = cn;
            const float hv = sig_(ov) * tanh_(cn);
            if (lmod < 8) {
                const ushort hh = f2bf(hv);
                const ushort hl = f2bf(hv - bf2f(hh));
                const uint32_t pk = (uint32_t)hh | ((uint32_t)hl << 16);
                const int row = lhi * 4 + e;
                hd[wb][row * 68 + d] = pk;
                h_pack[((size_t)(rbase + row) * T_STEPS + t) * HDIM + d] = pk;
            }
        }

        // unpack prefetched emb for next step
        {
            const uint32_t q[16] = {p0.x, p0.y, p0.z, p0.w, p1.x, p1.y, p1.z, p1.w,
                                    p2.x, p2.y, p2.z, p2.w, p3.x, p3.y, p3.z, p3.w};
#pragma unroll
            for (int kt = 0; kt < 2; ++kt) {
                short8 a_, b_;
#pragma unroll
                for (int e = 0; e < 8; ++e) {
                    a_[e] = (short)(q[kt * 8 + e] & 0xffffu);
                    b_[e] = (short)(q[kt * 8 + e] >> 16);
                }
                aeh[kt] = a_; ael[kt] = b_;
            }
        }
        __syncthreads();   // the ONLY barrier per step
    }
}

// ===== Kernel B: logits GEMM, LDS-free (frags preloaded from global) =========
__global__ __launch_bounds__(256) void lstm_logits2(
    const uint32_t* __restrict__ h_pack,
    const ushort*   __restrict__ lm_frag,
    const float*    __restrict__ lm_b,
    float*          __restrict__ out)
{
    const int tid  = threadIdx.x;
    const int wave = tid >> 6;
    const int lane = tid & 63;
    const int lmod = lane & 15;
    const int lhi  = lane >> 4;
    const size_t row0 = (size_t)blockIdx.x * 64 + wave * 16;

    short8 ah[2], al[2];
#pragma unroll
    for (int kt = 0; kt < 2; ++kt) {
        const uint32_t* src = h_pack + (row0 + lmod) * HDIM + kt * 32 + lhi * 8;
        const uint4 q0 = *(const uint4*)(src);
        const uint4 q1 = *(const uint4*)(src + 4);
        const uint32_t q[8] = {q0.x, q0.y, q0.z, q0.w, q1.x, q1.y, q1.z, q1.w};
        short8 a_, b_;
#pragma unroll
        for (int e = 0; e < 8; ++e) {
            a_[e] = (short)(q[e] & 0xffffu);
            b_[e] = (short)(q[e] >> 16);
        }
        ah[kt] = a_; al[kt] = b_;
    }

#pragma unroll 4
    for (int n = 0; n < 17; ++n) {
        const short8 bh0 = *(const short8*)(lm_frag + ((n * 2 + 0) * 512 + lane * 8));
        const short8 bh1 = *(const short8*)(lm_frag + ((n * 2 + 1) * 512 + lane * 8));
        const int v = n * 16 + lmod;
        const float bias = (v < VOCABSZ) ? lm_b[v] : 0.f;
        f32x4 acc = {bias, bias, bias, bias};
        acc = __builtin_amdgcn_mfma_f32_16x16x32_bf16(ah[0], bh0, acc, 0, 0, 0);
        acc = __builtin_amdgcn_mfma_f32_16x16x32_bf16(al[0], bh0, acc, 0, 0, 0);
        acc = __builtin_amdgcn_mfma_f32_16x16x32_bf16(ah[1], bh1, acc, 0, 0, 0);
        acc = __builtin_amdgcn_mfma_f32_16x16x32_bf16(al[1], bh1, acc, 0, 0, 0);
        if (v < VOCABSZ) {
#pragma unroll
            for (int e = 0; e < 4; ++e)
                out[(row0 + lhi * 4 + e) * VOCABSZ + v] = acc[e];
        }
    }
}

// ===== Fallback: fused kernel (used only if ws too small) ====================
__global__ __launch_bounds__(512) void lstm_fused_fb(
    const int*   __restrict__ idx,
    const float* __restrict__ wte,
    const float* __restrict__ W_ih,
    const float* __restrict__ W_hh,
    const float* __restrict__ b_ih,
    const float* __restrict__ b_hh,
    const float* __restrict__ lm_W,
    const float* __restrict__ lm_b,
    float*       __restrict__ out)
{
    __shared__ __align__(16) ushort a_hi[16 * 128];
    __shared__ __align__(16) ushort a_lo[16 * 128];
    __shared__ float g_lds[8 * 260];
    __shared__ int   idx_lds[8][T_STEPS];

    const int tid  = threadIdx.x;
    const int wave = tid >> 6;
    const int lane = tid & 63;
    const int lmod = lane & 15;
    const int lhi  = lane >> 4;
    const int rbase = blockIdx.x * 8;

    short8 wbh[2][4], wbl[2][4];
    float  gbias[2];
#pragma unroll
    for (int n = 0; n < 2; ++n) {
        const int col = wave * 32 + n * 16 + lmod;
        gbias[n] = b_ih[col] + b_hh[col];
#pragma unroll
        for (int kt = 0; kt < 4; ++kt) {
            const int k0 = (kt & 1) * 32 + lhi * 8;
            const float* src = (kt < 2 ? W_ih : W_hh) + col * HDIM + k0;
            short8 h8, l8;
#pragma unroll
            for (int e = 0; e < 8; ++e) {
                float f   = src[e];
                ushort hh = f2bf(f);
                h8[e] = (short)hh;
                l8[e] = (short)f2bf(f - bf2f(hh));
            }
            wbh[n][kt] = h8; wbl[n][kt] = l8;
        }
    }
    short8 lmh[2][2];
    float  lmbias[2];
#pragma unroll
    for (int ni = 0; ni < 2; ++ni) {
        const int v = (2 * wave + ni) * 16 + lmod;
        lmbias[ni] = lm_b[v];
#pragma unroll
        for (int kt = 0; kt < 2; ++kt) {
            const int k0 = kt * 32 + lhi * 8;
            short8 h8;
#pragma unroll
            for (int e = 0; e < 8; ++e) h8[e] = (short)f2bf(lm_W[v * HDIM + k0 + e]);
            lmh[ni][kt] = h8;
        }
    }
    const float w256r = lm_W[256 * HDIM + lane];
    const float b256  = lm_b[256];

    for (int i = tid; i < 16 * 128; i += 512) { a_hi[i] = 0; a_lo[i] = 0; }
    for (int i = tid; i < 8 * T_STEPS; i += 512) {
        const int r = i / T_STEPS, tt = i % T_STEPS;
        idx_lds[r][tt] = idx[(rbase + r) * T_STEPS + tt];
    }
    __syncthreads();
    if (tid < 8 * 16) {
        const int r = tid >> 4, j4 = (tid & 15) * 4;
        const int token = idx_lds[r][0];
        const float4 vv = *(const float4*)(wte + (size_t)token * HDIM + j4);
        const float fv[4] = {vv.x, vv.y, vv.z, vv.w};
#pragma unroll
        for (int e = 0; e < 4; ++e) {
            const ushort hh = f2bf(fv[e]);
            const int ix = (r * 128 + j4 + e) ^ ((r & 7) << 3);
            a_hi[ix] = hh;
            a_lo[ix] = f2bf(fv[e] - bf2f(hh));
        }
    }
    __syncthreads();

    float cstate = 0.f;
    for (int t = 0; t < T_STEPS; ++t) {
        f32x4 acc0 = {gbias[0], gbias[0], gbias[0], gbias[0]};
        f32x4 acc1 = {gbias[1], gbias[1], gbias[1], gbias[1]};
#pragma unroll
        for (int kt = 0; kt < 4; ++kt) {
            const int ix = (lmod * 128 + kt * 32 + lhi * 8) ^ ((lmod & 7) << 3);
            const short8 ah = *(const short8*)(a_hi + ix);
            const short8 al = *(const short8*)(a_lo + ix);
            acc0 = __builtin_amdgcn_mfma_f32_16x16x32_bf16(ah, wbh[0][kt], acc0, 0, 0, 0);
            acc0 = __builtin_amdgcn_mfma_f32_16x16x32_bf16(ah, wbl[0][kt], acc0, 0, 0, 0);
            acc0 = __builtin_amdgcn_mfma_f32_16x16x32_bf16(al, wbh[0][kt], acc0, 0, 0, 0);
            acc1 = __builtin_amdgcn_mfma_f32_16x16x32_bf16(ah, wbh[1][kt], acc1, 0, 0, 0);
            acc1 = __builtin_amdgcn_mfma_f32_16x16x32_bf16(ah, wbl[1][kt], acc1, 0, 0, 0);
            acc1 = __builtin_amdgcn_mfma_f32_16x16x32_bf16(al, wbh[1][kt], acc1, 0, 0, 0);
        }
        if (lhi < 2) {
#pragma unroll
            for (int e = 0; e < 4; ++e) {
                const int row = lhi * 4 + e;
                g_lds[row * 260 + wave * 32 + lmod]      = acc0[e];
                g_lds[row * 260 + wave * 32 + 16 + lmod] = acc1[e];
            }
        }
        __syncthreads();
        float4 vv;
        const bool do_stage = (t + 1 < T_STEPS) && (tid < 8 * 16);
        const int sr = tid >> 4, sj4 = (tid & 15) * 4;
        if (do_stage) {
            const int token = idx_lds[sr][t + 1];
            vv = *(const float4*)(wte + (size_t)token * HDIM + sj4);
        }
        {
            const float* gr = g_lds + wave * 260;
            const float iv = gr[lane];
            const float fv = gr[64 + lane];
            const float gv = gr[128 + lane];
            const float ov = gr[192 + lane];
            const float cn = sig_(fv) * cstate + sig_(iv) * tanh_(gv);
            cstate = cn;
            const float hv = sig_(ov) * tanh_(cn);
            const ushort hh = f2bf(hv);
            const int ix = (wave * 128 + 64 + lane) ^ ((wave & 7) << 3);
            a_hi[ix] = hh;
            a_lo[ix] = f2bf(hv - bf2f(hh));
            float p256 = hv * w256r;
#pragma unroll
            for (int off = 32; off; off >>= 1) p256 += __shfl_xor(p256, off);
            if (lane == 0)
                out[(size_t)(rbase + wave) * (T_STEPS * VOCABSZ) + (size_t)t * VOCABSZ + 256]
                    = p256 + b256;
        }
        if (do_stage) {
            const float fv[4] = {vv.x, vv.y, vv.z, vv.w};
#pragma unroll
            for (int e = 0; e < 4; ++e) {
                const ushort hh = f2bf(fv[e]);
                const int ix = (sr * 128 + sj4 + e) ^ ((sr & 7) << 3);
                a_hi[ix] = hh;
                a_lo[ix] = f2bf(fv[e] - bf2f(hh));
            }
        }
        __syncthreads();
        short8 lah[2], lal[2];
#pragma unroll
        for (int kt = 0; kt < 2; ++kt) {
            const int ix = (lmod * 128 + 64 + kt * 32 + lhi * 8) ^ ((lmod & 7) << 3);
            lah[kt] = *(const short8*)(a_hi + ix);
            lal[kt] = *(const short8*)(a_lo + ix);
        }
#pragma unroll
        for (int ni = 0; ni < 2; ++ni) {
            f32x4 acc = {lmbias[ni], lmbias[ni], lmbias[ni], lmbias[ni]};
#pragma unroll
            for (int kt = 0; kt < 2; ++kt) {
                acc = __builtin_amdgcn_mfma_f32_16x16x32_bf16(lah[kt], lmh[ni][kt], acc, 0, 0, 0);
                acc = __builtin_amdgcn_mfma_f32_16x16x32_bf16(lal[kt], lmh[ni][kt], acc, 0, 0, 0);
            }
            const int v = (2 * wave + ni) * 16 + lmod;
            if (lhi < 2) {
#pragma unroll
                for (int e = 0; e < 4; ++e) {
                    const int r = rbase + lhi * 4 + e;
                    out[(size_t)r * (T_STEPS * VOCABSZ) + (size_t)t * VOCABSZ + v] = acc[e];
                }
            }
        }
    }
}

extern "C" void kernel_launch(void* const* d_in, const int* in_sizes, int n_in,
                              void* d_out, int out_size, void* d_ws, size_t ws_size,
                              hipStream_t stream) {
    const int*   idx  = (const int*)  d_in[0];
    const float* wte  = (const float*)d_in[1];
    const float* W_ih = (const float*)d_in[2];
    const float* W_hh = (const float*)d_in[3];
    const float* b_ih = (const float*)d_in[4];
    const float* b_hh = (const float*)d_in[5];
    const float* lm_W = (const float*)d_in[6];
    const float* lm_b = (const float*)d_in[7];
    float* out = (float*)d_out;

    const int B = in_sizes[0] / T_STEPS;                       // 4096
    const size_t hbytes  = (size_t)B * T_STEPS * HDIM * 4;     // 90.2 MB
    const size_t wbytes  = (size_t)VOCABSZ * HDIM * 4;         // 65.8 KB
    const size_t lbytes  = (size_t)17 * 2 * 512 * 2;           // 34.8 KB
    const size_t need    = hbytes + wbytes + lbytes;

    if (ws_size >= need) {
        uint32_t* h_pack   = (uint32_t*)d_ws;
        uint32_t* wte_pack = (uint32_t*)((char*)d_ws + hbytes);
        ushort*   lm_frag  = (ushort*)  ((char*)d_ws + hbytes + wbytes);

        prep_pack<<<(VOCABSZ * HDIM + 255) / 256, 256, 0, stream>>>(
            wte, lm_W, wte_pack, lm_frag);
        lstm_recur3<<<B / 16, 512, 0, stream>>>(
            idx, wte_pack, W_ih, W_hh, b_ih, b_hh, h_pack);
        lstm_logits2<<<(B * T_STEPS) / 64, 256, 0, stream>>>(
            h_pack, lm_frag, lm_b, out);
    } else {
        lstm_fused_fb<<<B / 8, 512, 0, stream>>>(idx, wte, W_ih, W_hh, b_ih, b_hh,
                                                 lm_W, lm_b, out);
    }
}

// Round 8
// 304.382 us; speedup vs baseline: 1.0235x; 1.0235x over previous
//
#include <hip/hip_runtime.h>
#include <hip/hip_bf16.h>
#include <stdint.h>

#define T_STEPS 86
#define HDIM    64
#define VOCABSZ 257

typedef __attribute__((ext_vector_type(8))) short short8;
typedef __attribute__((ext_vector_type(4))) float f32x4;

__device__ __forceinline__ ushort f2bf(float x){
    union { float f; uint32_t u; } v; v.f = x;
    uint32_t r = v.u + 0x7fffu + ((v.u >> 16) & 1u);
    return (ushort)(r >> 16);
}
__device__ __forceinline__ float bf2f(ushort h){
    union { uint32_t u; float f; } v; v.u = ((uint32_t)h) << 16;
    return v.f;
}
__device__ __forceinline__ float sig_(float x){
    return __fdividef(1.f, 1.f + __expf(-x));
}
__device__ __forceinline__ float tanh_(float x){
    float e = __expf(2.f * x);
    return 1.f - __fdividef(2.f, e + 1.f);
}

// ===== Prep 1: xg[tok][col] = dot(wte[tok], W_ih[col]) + b_ih[col] + b_hh[col]
// Exact fp32. Token-only dependence removes the whole x-side MFMA from the loop.
__global__ __launch_bounds__(256) void prep_xg(
    const float* __restrict__ wte,
    const float* __restrict__ W_ih,
    const float* __restrict__ b_ih,
    const float* __restrict__ b_hh,
    float*       __restrict__ xg)      // [257][256]
{
    const int tok = blockIdx.x;        // 0..256
    const int col = threadIdx.x;       // 0..255
    float acc = b_ih[col] + b_hh[col];
    const float* wr = wte  + (size_t)tok * HDIM;
    const float* wc = W_ih + (size_t)col * HDIM;
#pragma unroll 8
    for (int k = 0; k < HDIM; ++k) acc += wr[k] * wc[k];
    xg[tok * 256 + col] = acc;
}

// ===== Prep 2: lm_W into MFMA B-frag layout ==================================
__global__ __launch_bounds__(256) void prep_lm(
    const float* __restrict__ lm_W,
    ushort*      __restrict__ lm_frag)  // [17][2][512]
{
    const int i = blockIdx.x * 256 + threadIdx.x;
    if (i < 17 * 2 * 64) {
        const int n = i >> 7, rem = i & 127, kt = rem >> 6, l = rem & 63;
        const int col = n * 16 + (l & 15);
        const int k0  = kt * 32 + (l >> 4) * 8;
        short8 h8;
#pragma unroll
        for (int e = 0; e < 8; ++e)
            h8[e] = (col < VOCABSZ) ? (short)f2bf(lm_W[col * HDIM + k0 + e]) : (short)0;
        *(short8*)(lm_frag + (size_t)i * 8) = h8;
    }
}

// ===== Kernel A: recurrence ==================================================
// gates = xg[token] (exact, LDS-staged dbuf) + h(t-1) @ W_hh^T (12 MFMAs,
// 3-term bf16 split as 3 INDEPENDENT acc chains of depth 2).
// Raw s_barrier with lgkmcnt-only wait: h_pack HBM stores never drain in-loop.
__global__ __launch_bounds__(512) void lstm_recur5(
    const int*   __restrict__ idx,
    const float* __restrict__ xg,
    const float* __restrict__ W_hh,
    uint32_t*    __restrict__ h_pack)   // [B][T][64] dwords hi|lo
{
    __shared__ float  xg_s[2][16][260];          // padded stride
    __shared__ __align__(16) ushort hd_hi[2][16 * 64];  // XOR-swizzled
    __shared__ __align__(16) ushort hd_lo[2][16 * 64];
    __shared__ int idx_lds[16][T_STEPS];

    const int tid  = threadIdx.x;
    const int wave = tid >> 6;
    const int lane = tid & 63;
    const int lmod = lane & 15;
    const int lhi  = lane >> 4;
    const int rbase = blockIdx.x * 16;

    const int d    = wave * 8 + (lmod & 7);
    const int col0 = (lmod < 8) ? d       : 64 + d;    // i | f
    const int col1 = (lmod < 8) ? 128 + d : 192 + d;   // g | o

    // W_hh B-frags hi/lo (K=64 -> kt in {0,1})
    short8 wbh[2][2], wbl[2][2];
#pragma unroll
    for (int n = 0; n < 2; ++n) {
        const int col = n ? col1 : col0;
#pragma unroll
        for (int kt = 0; kt < 2; ++kt) {
            const float* src = W_hh + (size_t)col * HDIM + kt * 32 + lhi * 8;
            short8 h8, l8;
#pragma unroll
            for (int e = 0; e < 8; ++e) {
                const float f = src[e];
                const ushort hh = f2bf(f);
                h8[e] = (short)hh;
                l8[e] = (short)f2bf(f - bf2f(hh));
            }
            wbh[n][kt] = h8; wbl[n][kt] = l8;
        }
    }

    // stage idx; zero h double-buffers
    for (int i = tid; i < 16 * T_STEPS; i += 512) {
        const int r = i / T_STEPS, tt = i % T_STEPS;
        idx_lds[r][tt] = idx[(rbase + r) * T_STEPS + tt];
    }
    {
        ushort* p0 = &hd_hi[0][0];
        ushort* p1 = &hd_lo[0][0];
        for (int i = tid; i < 2 * 16 * 64; i += 512) { p0[i] = 0; p1[i] = 0; }
    }
    __syncthreads();

    // stage xg(t=0): 16 rows x 256 f32, thread (srow, scol8)
    const int srow = tid >> 5, scol8 = (tid & 31) * 8;
    {
        const int tok = idx_lds[srow][0];
        const float4 v0 = *(const float4*)(xg + tok * 256 + scol8);
        const float4 v1 = *(const float4*)(xg + tok * 256 + scol8 + 4);
        *(float4*)&xg_s[0][srow][scol8]     = v0;
        *(float4*)&xg_s[0][srow][scol8 + 4] = v1;
    }
    __syncthreads();

    float cst[4] = {0.f, 0.f, 0.f, 0.f};

    for (int t = 0; t < T_STEPS; ++t) {
        const int cur = t & 1, nxt = cur ^ 1;
        const int rb = cur ^ 1, wb = cur;

        // 1. issue xg(t+1) prefetch (fire early; consumed at step 6)
        float4 pv0, pv1;
        const bool stg = (t + 1 < T_STEPS);
        if (stg) {
            const int tok2 = idx_lds[srow][t + 1];
            pv0 = *(const float4*)(xg + tok2 * 256 + scol8);
            pv1 = *(const float4*)(xg + tok2 * 256 + scol8 + 4);
        }

        // 2. h(t-1) A-frags from swizzled LDS (no unpack VALU)
        short8 hfh[2], hfl[2];
#pragma unroll
        for (int kt = 0; kt < 2; ++kt) {
            const int off = lmod * 64 + ((kt * 32 + lhi * 8) ^ ((lmod & 7) << 3));
            hfh[kt] = *(const short8*)&hd_hi[rb][off];
            hfl[kt] = *(const short8*)&hd_lo[rb][off];
        }

        // 3. acc-init from staged xg (exact x-contribution incl. biases)
        float x0[4], x1[4];
#pragma unroll
        for (int e = 0; e < 4; ++e) {
            const int row = lhi * 4 + e;
            x0[e] = xg_s[cur][row][col0];
            x1[e] = xg_s[cur][row][col1];
        }

        // 4. h @ W_hh^T: 12 MFMAs, 6 independent chains of depth 2
        f32x4 a0a = {x0[0], x0[1], x0[2], x0[3]};
        f32x4 a1a = {x1[0], x1[1], x1[2], x1[3]};
        f32x4 a0b = {0.f, 0.f, 0.f, 0.f}, a0c = a0b, a1b = a0b, a1c = a0b;
#pragma unroll
        for (int kt = 0; kt < 2; ++kt) {
            a0a = __builtin_amdgcn_mfma_f32_16x16x32_bf16(hfh[kt], wbh[0][kt], a0a, 0, 0, 0);
            a0b = __builtin_amdgcn_mfma_f32_16x16x32_bf16(hfh[kt], wbl[0][kt], a0b, 0, 0, 0);
            a0c = __builtin_amdgcn_mfma_f32_16x16x32_bf16(hfl[kt], wbh[0][kt], a0c, 0, 0, 0);
            a1a = __builtin_amdgcn_mfma_f32_16x16x32_bf16(hfh[kt], wbh[1][kt], a1a, 0, 0, 0);
            a1b = __builtin_amdgcn_mfma_f32_16x16x32_bf16(hfh[kt], wbl[1][kt], a1b, 0, 0, 0);
            a1c = __builtin_amdgcn_mfma_f32_16x16x32_bf16(hfl[kt], wbh[1][kt], a1c, 0, 0, 0);
        }

        // 5. pair gates in-wave + elementwise LSTM
#pragma unroll
        for (int e = 0; e < 4; ++e) {
            const float a0 = a0a[e] + a0b[e] + a0c[e];
            const float a1 = a1a[e] + a1b[e] + a1c[e];
            const float q0 = __shfl_xor(a0, 8);
            const float q1 = __shfl_xor(a1, 8);
            const float iv = (lmod < 8) ? a0 : q0;
            const float fv = (lmod < 8) ? q0 : a0;
            const float gv = (lmod < 8) ? a1 : q1;
            const float ov = (lmod < 8) ? q1 : a1;
            const float cn = sig_(fv) * cst[e] + sig_(iv) * tanh_(gv);
            cst[e] = cn;
            const float hv = sig_(ov) * tanh_(cn);
            if (lmod < 8) {
                const int row = lhi * 4 + e;
                const ushort hh = f2bf(hv);
                const ushort hl = f2bf(hv - bf2f(hh));
                const int sw = d ^ ((row & 7) << 3);
                hd_hi[wb][row * 64 + sw] = hh;
                hd_lo[wb][row * 64 + sw] = hl;
                h_pack[((size_t)(rbase + row) * T_STEPS + t) * HDIM + d]
                    = (uint32_t)hh | ((uint32_t)hl << 16);   // fire-and-forget
            }
        }

        // 6. stage xg(t+1) into the other buffer
        if (stg) {
            *(float4*)&xg_s[nxt][srow][scol8]     = pv0;
            *(float4*)&xg_s[nxt][srow][scol8 + 4] = pv1;
        }

        // 7. raw barrier: LDS-only drain; HBM stores stay in flight
        asm volatile("s_waitcnt lgkmcnt(0)" ::: "memory");
        __builtin_amdgcn_s_barrier();
        asm volatile("" ::: "memory");
    }
}

// ===== Kernel B: logits GEMM, LDS-free =======================================
__global__ __launch_bounds__(256) void lstm_logits2(
    const uint32_t* __restrict__ h_pack,
    const ushort*   __restrict__ lm_frag,
    const float*    __restrict__ lm_b,
    float*          __restrict__ out)
{
    const int tid  = threadIdx.x;
    const int wave = tid >> 6;
    const int lane = tid & 63;
    const int lmod = lane & 15;
    const int lhi  = lane >> 4;
    const size_t row0 = (size_t)blockIdx.x * 64 + wave * 16;

    short8 ah[2], al[2];
#pragma unroll
    for (int kt = 0; kt < 2; ++kt) {
        const uint32_t* src = h_pack + (row0 + lmod) * HDIM + kt * 32 + lhi * 8;
        const uint4 q0 = *(const uint4*)(src);
        const uint4 q1 = *(const uint4*)(src + 4);
        const uint32_t q[8] = {q0.x, q0.y, q0.z, q0.w, q1.x, q1.y, q1.z, q1.w};
        short8 a_, b_;
#pragma unroll
        for (int e = 0; e < 8; ++e) {
            a_[e] = (short)(q[e] & 0xffffu);
            b_[e] = (short)(q[e] >> 16);
        }
        ah[kt] = a_; al[kt] = b_;
    }

#pragma unroll 4
    for (int n = 0; n < 17; ++n) {
        const short8 bh0 = *(const short8*)(lm_frag + ((n * 2 + 0) * 512 + lane * 8));
        const short8 bh1 = *(const short8*)(lm_frag + ((n * 2 + 1) * 512 + lane * 8));
        const int v = n * 16 + lmod;
        const float bias = (v < VOCABSZ) ? lm_b[v] : 0.f;
        f32x4 acc = {bias, bias, bias, bias};
        acc = __builtin_amdgcn_mfma_f32_16x16x32_bf16(ah[0], bh0, acc, 0, 0, 0);
        acc = __builtin_amdgcn_mfma_f32_16x16x32_bf16(al[0], bh0, acc, 0, 0, 0);
        acc = __builtin_amdgcn_mfma_f32_16x16x32_bf16(ah[1], bh1, acc, 0, 0, 0);
        acc = __builtin_amdgcn_mfma_f32_16x16x32_bf16(al[1], bh1, acc, 0, 0, 0);
        if (v < VOCABSZ) {
#pragma unroll
            for (int e = 0; e < 4; ++e)
                out[(row0 + lhi * 4 + e) * VOCABSZ + v] = acc[e];
        }
    }
}

// ===== Fallback: fused kernel (used only if ws too small) ====================
__global__ __launch_bounds__(512) void lstm_fused_fb(
    const int*   __restrict__ idx,
    const float* __restrict__ wte,
    const float* __restrict__ W_ih,
    const float* __restrict__ W_hh,
    const float* __restrict__ b_ih,
    const float* __restrict__ b_hh,
    const float* __restrict__ lm_W,
    const float* __restrict__ lm_b,
    float*       __restrict__ out)
{
    __shared__ __align__(16) ushort a_hi[16 * 128];
    __shared__ __align__(16) ushort a_lo[16 * 128];
    __shared__ float g_lds[8 * 260];
    __shared__ int   idx_lds[8][T_STEPS];

    const int tid  = threadIdx.x;
    const int wave = tid >> 6;
    const int lane = tid & 63;
    const int lmod = lane & 15;
    const int lhi  = lane >> 4;
    const int rbase = blockIdx.x * 8;

    short8 wbh[2][4], wbl[2][4];
    float  gbias[2];
#pragma unroll
    for (int n = 0; n < 2; ++n) {
        const int col = wave * 32 + n * 16 + lmod;
        gbias[n] = b_ih[col] + b_hh[col];
#pragma unroll
        for (int kt = 0; kt < 4; ++kt) {
            const int k0 = (kt & 1) * 32 + lhi * 8;
            const float* src = (kt < 2 ? W_ih : W_hh) + col * HDIM + k0;
            short8 h8, l8;
#pragma unroll
            for (int e = 0; e < 8; ++e) {
                float f   = src[e];
                ushort hh = f2bf(f);
                h8[e] = (short)hh;
                l8[e] = (short)f2bf(f - bf2f(hh));
            }
            wbh[n][kt] = h8; wbl[n][kt] = l8;
        }
    }
    short8 lmh[2][2];
    float  lmbias[2];
#pragma unroll
    for (int ni = 0; ni < 2; ++ni) {
        const int v = (2 * wave + ni) * 16 + lmod;
        lmbias[ni] = lm_b[v];
#pragma unroll
        for (int kt = 0; kt < 2; ++kt) {
            const int k0 = kt * 32 + lhi * 8;
            short8 h8;
#pragma unroll
            for (int e = 0; e < 8; ++e) h8[e] = (short)f2bf(lm_W[v * HDIM + k0 + e]);
            lmh[ni][kt] = h8;
        }
    }
    const float w256r = lm_W[256 * HDIM + lane];
    const float b256  = lm_b[256];

    for (int i = tid; i < 16 * 128; i += 512) { a_hi[i] = 0; a_lo[i] = 0; }
    for (int i = tid; i < 8 * T_STEPS; i += 512) {
        const int r = i / T_STEPS, tt = i % T_STEPS;
        idx_lds[r][tt] = idx[(rbase + r) * T_STEPS + tt];
    }
    __syncthreads();
    if (tid < 8 * 16) {
        const int r = tid >> 4, j4 = (tid & 15) * 4;
        const int token = idx_lds[r][0];
        const float4 vv = *(const float4*)(wte + (size_t)token * HDIM + j4);
        const float fv[4] = {vv.x, vv.y, vv.z, vv.w};
#pragma unroll
        for (int e = 0; e < 4; ++e) {
            const ushort hh = f2bf(fv[e]);
            const int ix = (r * 128 + j4 + e) ^ ((r & 7) << 3);
            a_hi[ix] = hh;
            a_lo[ix] = f2bf(fv[e] - bf2f(hh));
        }
    }
    __syncthreads();

    float cstate = 0.f;
    for (int t = 0; t < T_STEPS; ++t) {
        f32x4 acc0 = {gbias[0], gbias[0], gbias[0], gbias[0]};
        f32x4 acc1 = {gbias[1], gbias[1], gbias[1], gbias[1]};
#pragma unroll
        for (int kt = 0; kt < 4; ++kt) {
            const int ix = (lmod * 128 + kt * 32 + lhi * 8) ^ ((lmod & 7) << 3);
            const short8 ah = *(const short8*)(a_hi + ix);
            const short8 al = *(const short8*)(a_lo + ix);
            acc0 = __builtin_amdgcn_mfma_f32_16x16x32_bf16(ah, wbh[0][kt], acc0, 0, 0, 0);
            acc0 = __builtin_amdgcn_mfma_f32_16x16x32_bf16(ah, wbl[0][kt], acc0, 0, 0, 0);
            acc0 = __builtin_amdgcn_mfma_f32_16x16x32_bf16(al, wbh[0][kt], acc0, 0, 0, 0);
            acc1 = __builtin_amdgcn_mfma_f32_16x16x32_bf16(ah, wbh[1][kt], acc1, 0, 0, 0);
            acc1 = __builtin_amdgcn_mfma_f32_16x16x32_bf16(ah, wbl[1][kt], acc1, 0, 0, 0);
            acc1 = __builtin_amdgcn_mfma_f32_16x16x32_bf16(al, wbh[1][kt], acc1, 0, 0, 0);
        }
        if (lhi < 2) {
#pragma unroll
            for (int e = 0; e < 4; ++e) {
                const int row = lhi * 4 + e;
                g_lds[row * 260 + wave * 32 + lmod]      = acc0[e];
                g_lds[row * 260 + wave * 32 + 16 + lmod] = acc1[e];
            }
        }
        __syncthreads();
        float4 vv;
        const bool do_stage = (t + 1 < T_STEPS) && (tid < 8 * 16);
        const int sr = tid >> 4, sj4 = (tid & 15) * 4;
        if (do_stage) {
            const int token = idx_lds[sr][t + 1];
            vv = *(const float4*)(wte + (size_t)token * HDIM + sj4);
        }
        {
            const float* gr = g_lds + wave * 260;
            const float iv = gr[lane];
            const float fv = gr[64 + lane];
            const float gv = gr[128 + lane];
            const float ov = gr[192 + lane];
            const float cn = sig_(fv) * cstate + sig_(iv) * tanh_(gv);
            cstate = cn;
            const float hv = sig_(ov) * tanh_(cn);
            const ushort hh = f2bf(hv);
            const int ix = (wave * 128 + 64 + lane) ^ ((wave & 7) << 3);
            a_hi[ix] = hh;
            a_lo[ix] = f2bf(hv - bf2f(hh));
            float p256 = hv * w256r;
#pragma unroll
            for (int off = 32; off; off >>= 1) p256 += __shfl_xor(p256, off);
            if (lane == 0)
                out[(size_t)(rbase + wave) * (T_STEPS * VOCABSZ) + (size_t)t * VOCABSZ + 256]
                    = p256 + b256;
        }
        if (do_stage) {
            const float fv[4] = {vv.x, vv.y, vv.z, vv.w};
#pragma unroll
            for (int e = 0; e < 4; ++e) {
                const ushort hh = f2bf(fv[e]);
                const int ix = (sr * 128 + sj4 + e) ^ ((sr & 7) << 3);
                a_hi[ix] = hh;
                a_lo[ix] = f2bf(fv[e] - bf2f(hh));
            }
        }
        __syncthreads();
        short8 lah[2], lal[2];
#pragma unroll
        for (int kt = 0; kt < 2; ++kt) {
            const int ix = (lmod * 128 + 64 + kt * 32 + lhi * 8) ^ ((lmod & 7) << 3);
            lah[kt] = *(const short8*)(a_hi + ix);
            lal[kt] = *(const short8*)(a_lo + ix);
        }
#pragma unroll
        for (int ni = 0; ni < 2; ++ni) {
            f32x4 acc = {lmbias[ni], lmbias[ni], lmbias[ni], lmbias[ni]};
#pragma unroll
            for (int kt = 0; kt < 2; ++kt) {
                acc = __builtin_amdgcn_mfma_f32_16x16x32_bf16(lah[kt], lmh[ni][kt], acc, 0, 0, 0);
                acc = __builtin_amdgcn_mfma_f32_16x16x32_bf16(lal[kt], lmh[ni][kt], acc, 0, 0, 0);
            }
            const int v = (2 * wave + ni) * 16 + lmod;
            if (lhi < 2) {
#pragma unroll
                for (int e = 0; e < 4; ++e) {
                    const int r = rbase + lhi * 4 + e;
                    out[(size_t)r * (T_STEPS * VOCABSZ) + (size_t)t * VOCABSZ + v] = acc[e];
                }
            }
        }
    }
}

extern "C" void kernel_launch(void* const* d_in, const int* in_sizes, int n_in,
                              void* d_out, int out_size, void* d_ws, size_t ws_size,
                              hipStream_t stream) {
    const int*   idx  = (const int*)  d_in[0];
    const float* wte  = (const float*)d_in[1];
    const float* W_ih = (const float*)d_in[2];
    const float* W_hh = (const float*)d_in[3];
    const float* b_ih = (const float*)d_in[4];
    const float* b_hh = (const float*)d_in[5];
    const float* lm_W = (const float*)d_in[6];
    const float* lm_b = (const float*)d_in[7];
    float* out = (float*)d_out;

    const int B = in_sizes[0] / T_STEPS;                       // 4096
    const size_t hbytes  = (size_t)B * T_STEPS * HDIM * 4;     // 90.2 MB
    const size_t xbytes  = (size_t)VOCABSZ * 256 * 4;          // 263 KB
    const size_t lbytes  = (size_t)17 * 2 * 512 * 2;           // 34.8 KB
    const size_t need    = hbytes + xbytes + lbytes;

    if (ws_size >= need) {
        uint32_t* h_pack  = (uint32_t*)d_ws;
        float*    xg      = (float*)  ((char*)d_ws + hbytes);
        ushort*   lm_frag = (ushort*) ((char*)d_ws + hbytes + xbytes);

        prep_xg<<<VOCABSZ, 256, 0, stream>>>(wte, W_ih, b_ih, b_hh, xg);
        prep_lm<<<9, 256, 0, stream>>>(lm_W, lm_frag);
        lstm_recur5<<<B / 16, 512, 0, stream>>>(idx, xg, W_hh, h_pack);
        lstm_logits2<<<(B * T_STEPS) / 64, 256, 0, stream>>>(h_pack, lm_frag, lm_b, out);
    } else {
        lstm_fused_fb<<<B / 8, 512, 0, stream>>>(idx, wte, W_ih, W_hh, b_ih, b_hh,
                                                 lm_W, lm_b, out);
    }
}